// Round 8
// baseline (232.073 us; speedup 1.0000x reference)
//
#include <hip/hip_runtime.h>

// B=8, N=2048, DIN=DOUT=128, DA=2, NEG_SLOPE=0.2
// out[b,i,:] = sum_j mask[b,i,j]*w[b,j]*xv[b,j,:] / sum_j mask[b,i,j]*w[b,j]
//   w[b,j]  = exp( leaky(x@Wc[0])*Wcat[2] + leaky(x@Wc[1])*Wcat[3] )  (lr_row cancels)
//   xv      = x @ Wx^T + bx
// u: 8 B-fragment tiles per 32-k t-step (R1 layout). w separate (wcol).

typedef __bf16 bf16x8 __attribute__((ext_vector_type(8)));
typedef __bf16 bf16x4 __attribute__((ext_vector_type(4)));
typedef float  f32x4  __attribute__((ext_vector_type(4)));
typedef int    i32x4  __attribute__((ext_vector_type(4)));
typedef unsigned int u32;

#define MFMA_BF16(a, b, c) __builtin_amdgcn_mfma_f32_16x16x32_bf16((a), (b), (c), 0, 0, 0)

// async global->LDS; HW writes lane l at lds_base + l*16 (wave-uniform base).
#define GLOAD_LDS16(gp, lp)                                                     \
  __builtin_amdgcn_global_load_lds(                                             \
      (const __attribute__((address_space(1))) void*)(gp),                      \
      (__attribute__((address_space(3))) void*)(lp), 16, 0, 0)

static __device__ __forceinline__ bf16x8 cvt8(f32x4 a, f32x4 b) {
  bf16x8 r;
  r[0] = (__bf16)a[0]; r[1] = (__bf16)a[1]; r[2] = (__bf16)a[2]; r[3] = (__bf16)a[3];
  r[4] = (__bf16)b[0]; r[5] = (__bf16)b[1]; r[6] = (__bf16)b[2]; r[7] = (__bf16)b[3];
  return r;
}

// ---------------------------------------------------------------------------
// Kernel A (verified in R1-R5): per (b, 64 k-rows): w[k] -> wcol, and
// u[k][c] = w[k]*xv[k][c] pre-swizzled in mfma_16x16x32 B-fragment order:
//   elem(b,t,n,lane,j) = u[k = t*32 + (lane>>4)*8 + j][c = n*16 + (lane&15)]
//   at flat index (((b*64+t)*8+n)*64+lane)*8+j
// ---------------------------------------------------------------------------
__global__ __launch_bounds__(256) void prep_kernel(
    const float* __restrict__ x, const float* __restrict__ Wc,
    const float* __restrict__ Wcat, const float* __restrict__ Wx,
    const float* __restrict__ bx, __bf16* __restrict__ u,
    __bf16* __restrict__ wcol)
{
  __shared__ __bf16 lds[8192];  // 16 KB: 2 t-steps x 8 tiles x 64 lanes x 8
  const int blk = blockIdx.x;            // 256 blocks
  const int b = blk >> 5, mt = blk & 31; // 32 blocks/batch, 64 rows each
  const int wv = threadIdx.x >> 6, lane = threadIdx.x & 63;
  const int np = lane & 15, G = lane >> 4;
  const int r0 = mt * 64 + wv * 16;      // wave's 16 k-rows

  const float* xp = x + ((size_t)(b * 2048 + r0 + np)) * 128 + G * 8;
  bf16x8 af[4];
#pragma unroll
  for (int kk = 0; kk < 4; ++kk) {
    f32x4 x0 = *(const f32x4*)(xp + kk * 32);
    f32x4 x1 = *(const f32x4*)(xp + kk * 32 + 4);
    af[kk] = cvt8(x0, x1);
  }

  f32x4 acc[8], accC;
#pragma unroll
  for (int n = 0; n < 8; ++n) { acc[n][0] = 0.f; acc[n][1] = 0.f; acc[n][2] = 0.f; acc[n][3] = 0.f; }
  accC[0] = accC[1] = accC[2] = accC[3] = 0.f;

#pragma unroll
  for (int n = 0; n < 8; ++n) {
    const float* wp = Wx + (n * 16 + np) * 128 + G * 8;
#pragma unroll
    for (int kk = 0; kk < 4; ++kk) {
      f32x4 w0 = *(const f32x4*)(wp + kk * 32);
      f32x4 w1 = *(const f32x4*)(wp + kk * 32 + 4);
      acc[n] = MFMA_BF16(af[kk], cvt8(w0, w1), acc[n]);
    }
  }
#pragma unroll
  for (int kk = 0; kk < 4; ++kk) {
    bf16x8 bf;
    if (np < 2) {
      const float* cp = Wc + np * 128 + kk * 32 + G * 8;
      f32x4 c0 = *(const f32x4*)cp;
      f32x4 c1 = *(const f32x4*)(cp + 4);
      bf = cvt8(c0, c1);
    } else {
#pragma unroll
      for (int j = 0; j < 8; ++j) bf[j] = (__bf16)0.0f;
    }
    accC = MFMA_BF16(af[kk], bf, accC);
  }

  const float a20 = Wcat[2], a21 = Wcat[3];
  float wexp[4];
#pragma unroll
  for (int r = 0; r < 4; ++r) {
    float c0 = __shfl(accC[r], lane & 48);
    float c1 = __shfl(accC[r], (lane & 48) | 1);
    c0 = c0 > 0.f ? c0 : 0.2f * c0;
    c1 = c1 > 0.f ? c1 : 0.2f * c1;
    wexp[r] = __expf(c0 * a20 + c1 * a21);
  }
  if (np == 0) {  // lanes 0,16,32,48 write w for rows r0+4G+{0..3}
    bf16x4 w4;
#pragma unroll
    for (int r = 0; r < 4; ++r) w4[r] = (__bf16)wexp[r];
    *(bf16x4*)(wcol + (size_t)b * 2048 + r0 + 4 * G) = w4;
  }

  const int t_rel = wv >> 1;
  const int g_store = (wv & 1) * 2 + (G >> 1);
  const int j0 = (G & 1) * 4;
#pragma unroll
  for (int n = 0; n < 8; ++n) {
    float bxv = bx[n * 16 + np];
    bf16x4 v;
#pragma unroll
    for (int r = 0; r < 4; ++r) v[r] = (__bf16)(wexp[r] * (acc[n][r] + bxv));
    *(bf16x4*)(&lds[(t_rel * 8 + n) * 512 + g_store * 128 + np * 8 + j0]) = v;
  }
  __syncthreads();
  __bf16* dst = u + ((size_t)(b * 64 + mt * 2)) * 4096;
#pragma unroll
  for (int it = 0; it < 4; ++it) {
    int s = it * 256 + threadIdx.x;
    ((i32x4*)dst)[s] = ((const i32x4*)lds)[s];
  }
}

// ---------------------------------------------------------------------------
// Kernel B v8: T3+T4 counted-vmcnt pipeline. v6/v7 stalled ~4.7k cy/iter on
// the __syncthreads-implied vmcnt(0) drain of the just-issued prefetch.
// Now: 4-buffer ring (BK=32), stage = exactly 3 gload_lds/wave (1 mask +
// 2 u), raw s_barrier, s_waitcnt vmcnt(6) in the main loop (2 stages stay
// in flight across barriers; never drains to 0). Denominator via VALU from
// a broadcast w-fragment (LDS, staged once) - drops the 9th u tile.
// Liveness: stage(it+3) overwrites buf[(it-1)&3]; all consumers of that
// buffer crossed the iter-it barrier (vmcnt precedes barrier, so every
// wave's stage(it) landed before anyone proceeds).
// ---------------------------------------------------------------------------
__global__ __launch_bounds__(256) void attn_kernel(
    const int* __restrict__ mask, const __bf16* __restrict__ u,
    const __bf16* __restrict__ wcol, float* __restrict__ out)
{
  __shared__ char smem[4 * 12288 + 4096];  // 4 ring bufs (mask 4K + u 8K) + wbuf 4K
  char* wbuf = smem + 49152;
  const int b = blockIdx.x & 7, rt = blockIdx.x >> 3;  // 8 x 64 (batch->XCD pin)
  const int wv = threadIdx.x >> 6, lane = threadIdx.x & 63;
  const int np = lane & 15, G = lane >> 4;
  const int row0 = rt * 32;
  const int n0 = wv * 2, n1 = n0 + 1;
  const int swzB = (np & 7) << 4;          // read-side XOR swizzle (bytes)

  const char* gmask = (const char*)(mask + ((size_t)b * 2048 + row0) * 2048);
  const char* gu    = (const char*)u + (size_t)b * 64 * 8192;
  const char* gw    = (const char*)(wcol + (size_t)b * 2048);

  // mask staging: wave wv covers tile rows 8wv..8wv+7; lane l -> row 8wv+(l>>3),
  // slot l&7; source slot pre-XORed so LDS[row][s] = G_row[s ^ (row&7)].
  const int srow = lane >> 3;
  const long long moff = (size_t)(8 * wv + srow) * 8192 + (((lane & 7) ^ srow) << 4);

  f32x4 acc[2][2];
#pragma unroll
  for (int mi = 0; mi < 2; ++mi)
#pragma unroll
    for (int n = 0; n < 2; ++n) { acc[mi][n][0] = 0.f; acc[mi][n][1] = 0.f; acc[mi][n][2] = 0.f; acc[mi][n][3] = 0.f; }
  float den[2] = {0.f, 0.f};

#define STAGE(it, nb)                                                          \
  do {                                                                         \
    char* mb_ = smem + (nb) * 12288;                                           \
    GLOAD_LDS16(gmask + moff + (it) * 128, mb_ + wv * 1024);                   \
    const char* up_ = gu + (size_t)(it) * 8192 + lane * 16;                    \
    GLOAD_LDS16(up_ + (2 * wv) * 1024, mb_ + 4096 + (2 * wv) * 1024);          \
    GLOAD_LDS16(up_ + (2 * wv + 1) * 1024, mb_ + 4096 + (2 * wv + 1) * 1024);  \
  } while (0)

#define CONSUME(it, nb)                                                        \
  do {                                                                         \
    const char* mb = smem + (nb) * 12288;                                      \
    const char* ub = mb + 4096;                                                \
    bf16x8 W = *(const bf16x8*)(wbuf + (it) * 64 + G * 16);                    \
    float wf[8];                                                               \
    _Pragma("unroll")                                                          \
    for (int j = 0; j < 8; ++j) wf[j] = (float)W[j];                           \
    bf16x8 U0 = *(const bf16x8*)(ub + n0 * 1024 + lane * 16);                  \
    bf16x8 U1 = *(const bf16x8*)(ub + n1 * 1024 + lane * 16);                  \
    _Pragma("unroll")                                                          \
    for (int mi = 0; mi < 2; ++mi) {                                           \
      const char* rp = mb + (mi * 16 + np) * 128;                              \
      i32x4 ma = *(const i32x4*)(rp + ((G * 32) ^ swzB));                      \
      i32x4 mz = *(const i32x4*)(rp + ((G * 32 + 16) ^ swzB));                 \
      union { u32 w[4]; bf16x8 v; } A;                                         \
      A.w[0] = (ma[0] ? 0x3F80u : 0u) | (ma[1] ? 0x3F800000u : 0u);            \
      A.w[1] = (ma[2] ? 0x3F80u : 0u) | (ma[3] ? 0x3F800000u : 0u);            \
      A.w[2] = (mz[0] ? 0x3F80u : 0u) | (mz[1] ? 0x3F800000u : 0u);            \
      A.w[3] = (mz[2] ? 0x3F80u : 0u) | (mz[3] ? 0x3F800000u : 0u);            \
      float d = den[mi];                                                       \
      d += ma[0] ? wf[0] : 0.f; d += ma[1] ? wf[1] : 0.f;                      \
      d += ma[2] ? wf[2] : 0.f; d += ma[3] ? wf[3] : 0.f;                      \
      d += mz[0] ? wf[4] : 0.f; d += mz[1] ? wf[5] : 0.f;                      \
      d += mz[2] ? wf[6] : 0.f; d += mz[3] ? wf[7] : 0.f;                      \
      den[mi] = d;                                                             \
      acc[mi][0] = MFMA_BF16(A.v, U0, acc[mi][0]);                             \
      acc[mi][1] = MFMA_BF16(A.v, U1, acc[mi][1]);                             \
    }                                                                          \
  } while (0)

  // prologue: wbuf (1 instr/wave) + ring stages 0,1,2 (9 instrs/wave)
  GLOAD_LDS16(gw + wv * 1024 + lane * 16, wbuf + wv * 1024);
  STAGE(0, 0); STAGE(1, 1); STAGE(2, 2);

  for (int it = 0; it <= 61; ++it) {
    asm volatile("s_waitcnt vmcnt(6)" ::: "memory");  // keep 2 stages in flight
    __builtin_amdgcn_s_barrier();
    CONSUME(it, it & 3);
    if (it <= 60) STAGE(it + 3, (it + 3) & 3);
  }
  asm volatile("s_waitcnt vmcnt(3)" ::: "memory");
  __builtin_amdgcn_s_barrier();
  CONSUME(62, 2);
  asm volatile("s_waitcnt vmcnt(0)" ::: "memory");
  __builtin_amdgcn_s_barrier();
  CONSUME(63, 3);
#undef STAGE
#undef CONSUME

  // epilogue: reduce den over G (lanes np, np+16, np+32, np+48), then
  // D row = mi*16 + 4G + r (col = n*16+np); den for that row lives at lane 4G+r.
#pragma unroll
  for (int mi = 0; mi < 2; ++mi) {
    float dr = den[mi] + __shfl_xor(den[mi], 16);
    dr += __shfl_xor(dr, 32);
#pragma unroll
    for (int r = 0; r < 4; ++r) {
      float dv = __shfl(dr, 4 * G + r);
      float inv = 1.0f / dv;
      float* op = out + ((size_t)b * 2048 + row0 + mi * 16 + 4 * G + r) * 128 + np;
      op[n0 * 16] = acc[mi][0][r] * inv;
      op[n1 * 16] = acc[mi][1][r] * inv;
    }
  }
}

extern "C" void kernel_launch(void* const* d_in, const int* in_sizes, int n_in,
                              void* d_out, int out_size, void* d_ws, size_t ws_size,
                              hipStream_t stream) {
  const float* x    = (const float*)d_in[0];
  const int*   mask = (const int*)d_in[1];
  // d_in[2] = Wr : unused (lr_row cancels in softmax over j)
  const float* Wc   = (const float*)d_in[3];
  const float* Wcat = (const float*)d_in[4];
  const float* Wx   = (const float*)d_in[5];
  const float* bx   = (const float*)d_in[6];
  float* out = (float*)d_out;

  // workspace: u (8*64*4096 bf16 = 4 MB) + wcol (8*2048 bf16 = 32 KB)
  const size_t U_BYTES = (size_t)8 * 64 * 4096 * 2;
  if (ws_size < U_BYTES + 8 * 2048 * 2) return;  // insufficient scratch
  __bf16* u    = (__bf16*)d_ws;
  __bf16* wcol = (__bf16*)((char*)d_ws + U_BYTES);

  prep_kernel<<<256, 256, 0, stream>>>(x, Wc, Wcat, Wx, bx, u, wcol);
  attn_kernel<<<512, 256, 0, stream>>>(mask, u, wcol, out);
}